// Round 8
// baseline (404.925 us; speedup 1.0000x reference)
//
#include <hip/hip_runtime.h>

typedef unsigned int u32;
typedef unsigned char u8;

#define M_DIM 8192   // B*S = 4*2048
#define K_DIM 4096   // I
#define N_DIM 4096   // O
#define GROUPS 64    // I / GROUP_SIZE

typedef int intx4 __attribute__((ext_vector_type(4)));

__device__ __forceinline__ void gload_lds16(const void* g, void* l) {
  __builtin_amdgcn_global_load_lds(
      (const __attribute__((address_space(1))) void*)g,
      (__attribute__((address_space(3))) void*)l, 16, 0, 0);
}

__device__ __forceinline__ u32 pack4(const float* v, float inv) {
  u32 r = 0;
#pragma unroll
  for (int i = 0; i < 4; ++i) {
    int q = (int)__builtin_rintf(v[i] * inv);
    q = q > 127 ? 127 : (q < -127 ? -127 : q);
    r |= ((u32)(u8)(char)q) << (8 * i);
  }
  return r;
}

// ---- fused prep ----
// blocks [0, N_DIM): W path — one weight row per 256-thread block: dequant,
//   scatter via perm into LDS rowbuf, block absmax, quantize (verified).
// blocks [N_DIM, N_DIM + M_DIM/4): X path — one x row per WAVE (4 rows per
//   block). No __syncthreads, no LDS: wave shuffle reduce only, 16 float4
//   pairs in flight per lane. Roofline ~25 us for the whole X side.
__global__ __launch_bounds__(256) void prep_all(
    const float* __restrict__ x, const float* __restrict__ cs,
    const u32* __restrict__ qw, const int* __restrict__ perm,
    const float* __restrict__ scales, const float* __restrict__ zeros,
    u8* __restrict__ xq, u8* __restrict__ wq,
    float* __restrict__ sx, float* __restrict__ sw) {
  __shared__ float rowbuf[K_DIM];   // 16 KB (W path only)
  __shared__ float red[4];
  const int t = threadIdx.x;
  if (blockIdx.x < N_DIM) {
    // ---- W path (unchanged, verified) ----
    const int base = t * 16;
    const int o = blockIdx.x;
    const u32* qrow = qw + (size_t)o * (K_DIM / 8);
    const float s = scales[o * GROUPS + (t >> 2)];
    const float z = zeros[o * GROUPS + (t >> 2)];
    uint2 w = *(const uint2*)(qrow + 2 * t);   // elements [16t, 16t+16)
    int4 p0 = *(const int4*)(perm + base + 0);
    int4 p1 = *(const int4*)(perm + base + 4);
    int4 p2 = *(const int4*)(perm + base + 8);
    int4 p3 = *(const int4*)(perm + base + 12);
    float v[16];
    float amax = 0.f;
#pragma unroll
    for (int n = 0; n < 8; ++n) {
      v[n]     = (float)((w.x >> (4 * n)) & 15u) * s + z;
      v[8 + n] = (float)((w.y >> (4 * n)) & 15u) * s + z;
      amax = fmaxf(amax, fmaxf(fabsf(v[n]), fabsf(v[8 + n])));
    }
    rowbuf[p0.x] = v[0];  rowbuf[p0.y] = v[1];
    rowbuf[p0.z] = v[2];  rowbuf[p0.w] = v[3];
    rowbuf[p1.x] = v[4];  rowbuf[p1.y] = v[5];
    rowbuf[p1.z] = v[6];  rowbuf[p1.w] = v[7];
    rowbuf[p2.x] = v[8];  rowbuf[p2.y] = v[9];
    rowbuf[p2.z] = v[10]; rowbuf[p2.w] = v[11];
    rowbuf[p3.x] = v[12]; rowbuf[p3.y] = v[13];
    rowbuf[p3.z] = v[14]; rowbuf[p3.w] = v[15];
    // block absmax (wave butterfly + LDS cross-wave); syncthreads inside
    // also orders rowbuf for the re-read below
#pragma unroll
    for (int off = 32; off; off >>= 1)
      amax = fmaxf(amax, __shfl_xor(amax, off, 64));
    if ((t & 63) == 0) red[t >> 6] = amax;
    __syncthreads();
    amax = fmaxf(fmaxf(red[0], red[1]), fmaxf(red[2], red[3]));
    amax = fmaxf(amax, 1e-20f);
    const float inv = 127.0f / amax;
    uint4 p;
    p.x = pack4(rowbuf + base + 0, inv);
    p.y = pack4(rowbuf + base + 4, inv);
    p.z = pack4(rowbuf + base + 8, inv);
    p.w = pack4(rowbuf + base + 12, inv);
    *(uint4*)(wq + (size_t)o * K_DIM + base) = p;
    if (t == 0) sw[o] = amax * (1.0f / 127.0f);
  } else {
    // ---- X path: one row per wave ----
    const int wave = t >> 6, lane = t & 63;
    const size_t m = (size_t)(blockIdx.x - N_DIM) * 4 + wave;
    const float* xr = x + m * K_DIM;
    float v[64];
    float amax = 0.f;
#pragma unroll
    for (int j = 0; j < 4; ++j) {
      const int col = j * 1024 + lane * 16;   // 16 consecutive elems
#pragma unroll
      for (int u = 0; u < 4; ++u) {
        float4 xv = *(const float4*)(xr + col + u * 4);
        float4 cv = *(const float4*)(cs + col + u * 4);
        float* vp = v + j * 16 + u * 4;
        vp[0] = xv.x * cv.x;
        vp[1] = xv.y * cv.y;
        vp[2] = xv.z * cv.z;
        vp[3] = xv.w * cv.w;
        amax = fmaxf(amax, fmaxf(fmaxf(fabsf(vp[0]), fabsf(vp[1])),
                                 fmaxf(fabsf(vp[2]), fabsf(vp[3]))));
      }
    }
#pragma unroll
    for (int off = 32; off; off >>= 1)
      amax = fmaxf(amax, __shfl_xor(amax, off, 64));
    amax = fmaxf(amax, 1e-20f);
    const float inv = 127.0f / amax;
#pragma unroll
    for (int j = 0; j < 4; ++j) {
      uint4 p;
      p.x = pack4(v + j * 16 + 0, inv);
      p.y = pack4(v + j * 16 + 4, inv);
      p.z = pack4(v + j * 16 + 8, inv);
      p.w = pack4(v + j * 16 + 12, inv);
      *(uint4*)(xq + m * K_DIM + j * 1024 + lane * 16) = p;
    }
    if (lane == 0) sx[m] = amax * (1.0f / 127.0f);
  }
}

// ---- gemm: 128x128 tile, 4 waves, 16x16x64 i8 ----
// DISTANCE-2 prefetch x multi-block TLP — the untried cell. Five schedules
// all pinned MfmaUtil at ~30%: common cause is per-tile load-latency stall
// (compute window ~82-326 cyc vs L2/HBM latency 200-900 cyc, m126).
// Here: 3 LDS buffers (48 KB -> up to 3 blocks/CU by LDS; VGPR ~70),
// stage tile t+2 during tile t, counted vmcnt(4) certifies t+1 only
// (t+2's 4 loads stay in flight) -> per-tile stall = latency - ~1.5
// tile-times, residue covered by independent blocks (m114 cross-block
// overlap; blocks don't share barriers).
// LDS scheme: round-0 verified-zero-conflict. Chunk c: row r=c>>2, slot
// p=c&3 holds global chunk p ^ ((r>>1)&3) (pre-swizzled source, linear
// dest); frag read slot qs = q ^ ((lr>>1)&3). 32x32 frags abandoned
// (fixed 1.26e7-conflict tax, swizzle-invariant).
// __launch_bounds__(256,2): NEVER raise the 2nd arg (round-4 spill: (512,4)
// forced a 64-VGPR cap -> 13 GB scratch traffic).
#define BM 128
#define BN 128
#define BK 64
#define KTILES (K_DIM / BK)   // 64

__global__ __launch_bounds__(256, 2) void gemm_i8(
    const u8* __restrict__ A, const u8* __restrict__ B,
    const float* __restrict__ sx, const float* __restrict__ sw,
    const float* __restrict__ bias, float* __restrict__ out) {
  __shared__ __align__(16) u8 As[3][BM * BK];   // 3 x 8 KB
  __shared__ __align__(16) u8 Bs[3][BN * BK];   // 3 x 8 KB
  const int tid = threadIdx.x;
  const int lane = tid & 63;
  const int wave = tid >> 6;           // 0..3
  const int wm = wave >> 1;            // 0..1 -> 64 M-rows
  const int wn = wave & 1;             // 0..1 -> 64 N-cols
  const int q = lane >> 4, lr = lane & 15;
  const int qs = q ^ ((lr >> 1) & 3);  // verified conflict-free read slot

  // XCD-aware bijective swizzle (2048 % 8 == 0)
  const int wg = blockIdx.x;
  const int swzwg = (wg & 7) * 256 + (wg >> 3);
  const int blockN = (swzwg & 31) * BN;
  const int blockM = (swzwg >> 5) * BM;

  const char* Abase = (const char*)(A + (size_t)blockM * K_DIM);
  const char* Bbase = (const char*)(B + (size_t)blockN * K_DIM);

  const int c0 = tid, c1 = tid + 256;
  const int kc0 = (c0 & 3) ^ ((c0 >> 3) & 3);
  const int kc1 = (c1 & 3) ^ ((c1 >> 3) & 3);
  const size_t gOff0 = (size_t)(c0 >> 2) * K_DIM + kc0 * 16;
  const size_t gOff1 = (size_t)(c1 >> 2) * K_DIM + kc1 * 16;
  const int dOff0 = c0 * 16, dOff1 = c1 * 16;

  const int aoff = (wm * 64 + lr) * 64 + qs * 16;   // + mi*1024
  const int boff = (wn * 64 + lr) * 64 + qs * 16;   // + ni*1024

  intx4 acc[4][4];
#pragma unroll
  for (int i = 0; i < 4; ++i)
#pragma unroll
    for (int j = 0; j < 4; ++j) acc[i][j] = (intx4)0;

  auto stage = [&](int t, int b) {
    const size_t koff = (size_t)t * BK;
    gload_lds16(Abase + gOff0 + koff, &As[b][dOff0]);
    gload_lds16(Abase + gOff1 + koff, &As[b][dOff1]);
    gload_lds16(Bbase + gOff0 + koff, &Bs[b][dOff0]);
    gload_lds16(Bbase + gOff1 + koff, &Bs[b][dOff1]);
  };

  // prologue: tiles 0,1 in flight; certify tile 0 (tile 1 keeps flying)
  stage(0, 0);
  stage(1, 1);
  asm volatile("s_waitcnt vmcnt(4)" ::: "memory");
  asm volatile("s_barrier" ::: "memory");

  int bc = 0, bs = 2;   // compute buf for t; stage buf for t+2
  for (int t = 0; t < KTILES; ++t) {
    if (t + 2 < KTILES) stage(t + 2, bs);

    const u8* Ab = &As[bc][0];
    const u8* Bb = &Bs[bc][0];
    intx4 af[4], bf[4];
#pragma unroll
    for (int mi = 0; mi < 4; ++mi)
      af[mi] = *(const intx4*)(Ab + aoff + mi * 1024);
#pragma unroll
    for (int ni = 0; ni < 4; ++ni)
      bf[ni] = *(const intx4*)(Bb + boff + ni * 1024);

    __builtin_amdgcn_s_setprio(1);
#pragma unroll
    for (int mi = 0; mi < 4; ++mi)
#pragma unroll
      for (int ni = 0; ni < 4; ++ni)
        acc[mi][ni] = __builtin_amdgcn_mfma_i32_16x16x64_i8(
            af[mi], bf[ni], acc[mi][ni], 0, 0, 0);
    __builtin_amdgcn_s_setprio(0);

    // certify t+1 before next tile; t+2's loads stay in flight
    if (t + 2 < KTILES) {
      asm volatile("s_waitcnt vmcnt(4)" ::: "memory");
    } else if (t + 1 < KTILES) {
      asm volatile("s_waitcnt vmcnt(0)" ::: "memory");   // pipeline drain
    }
    if (t + 1 < KTILES) asm volatile("s_barrier" ::: "memory");

    bc = (bc == 2) ? 0 : bc + 1;
    bs = (bs == 2) ? 0 : bs + 1;
  }

  // epilogue (round-0 verified): col slot = lane&15, row = quad*4 + reg
#pragma unroll
  for (int ni = 0; ni < 4; ++ni) {
    const int col = blockN + wn * 64 + ni * 16 + lr;
    const float swv = sw[col];
    const float bv = bias[col];
#pragma unroll
    for (int mi = 0; mi < 4; ++mi) {
      const int row0 = blockM + wm * 64 + mi * 16 + q * 4;
#pragma unroll
      for (int r = 0; r < 4; ++r) {
        const float s = sx[row0 + r] * swv;
        out[(size_t)(row0 + r) * N_DIM + col] = (float)acc[mi][ni][r] * s + bv;
      }
    }
  }
}

extern "C" void kernel_launch(void* const* d_in, const int* in_sizes, int n_in,
                              void* d_out, int out_size, void* d_ws, size_t ws_size,
                              hipStream_t stream) {
  const float* x      = (const float*)d_in[0];
  const float* cs     = (const float*)d_in[1];
  const u32*   qw     = (const u32*)d_in[2];
  const int*   perm   = (const int*)d_in[3];
  const float* scales = (const float*)d_in[4];
  const float* zeros  = (const float*)d_in[5];
  const float* bias   = (const float*)d_in[6];
  float* out = (float*)d_out;

  u8* xq = (u8*)d_ws;                               // 32 MiB: M*K i8 (natural)
  u8* wq = xq + (size_t)M_DIM * K_DIM;              // 16 MiB: N*K i8 (perm-scattered)
  float* sx = (float*)(wq + (size_t)N_DIM * K_DIM); // 32 KiB
  float* sw = sx + M_DIM;                           // 16 KiB

  hipLaunchKernelGGL(prep_all, dim3(N_DIM + M_DIM / 4), dim3(256), 0, stream,
                     x, cs, qw, perm, scales, zeros, xq, wq, sx, sw);
  hipLaunchKernelGGL(gemm_i8, dim3((M_DIM / BM) * (N_DIM / BN)), dim3(256), 0,
                     stream, xq, wq, sx, sw, bias, out);
}